// Round 1
// baseline (7617.352 us; speedup 1.0000x reference)
//
#include <hip/hip_runtime.h>
#include <hip/hip_fp16.h>

typedef _Float16 half_t;
typedef _Float16 half2_t __attribute__((ext_vector_type(2)));
typedef unsigned int u32;

#define SEQ   512
#define HID   512
#define BATCH 64
#define NSK   1024
#define INDIM 2048
#define G4    2048   // 4*HID gate rows

// h[t] pair layout: u32 word (k2*64 + b) holds halves (h[2k2][b], h[2k2+1][b]).
#define HWORDS 16384   // u32 words per timestep (64 KB)
#define HHALF  32768   // half elements per timestep

// ---- workspace layout (bytes) ----
#define H1_OFF    0ull
#define H2_OFF    33554432ull
#define C0_OFF    67108864ull
#define C1_OFF    67239936ull
#define B0_OFF    67371008ull
#define B1_OFF    67379200ull
#define WHH0_OFF  67387392ull
#define WIH1_OFF  69484544ull
#define WHH1_OFF  71581696ull
#define FCW_OFF   73678848ull
#define WS_NEED   74727424ull

__device__ __forceinline__ float sigmoidf_(float x) {
    return 1.0f / (1.0f + __expf(-x));
}
__device__ __forceinline__ float tanhf_(float x) {
    return 2.0f * sigmoidf_(2.0f * x) - 1.0f;   // exact identity; saturates correctly
}

__device__ __forceinline__ float dot2_(u32 a, u32 b, float c) {
    half2_t ha = __builtin_bit_cast(half2_t, a);
    half2_t hb = __builtin_bit_cast(half2_t, b);
#if __has_builtin(__builtin_amdgcn_fdot2)
    return __builtin_amdgcn_fdot2(ha, hb, c, false);
#else
    return c + (float)ha[0] * (float)hb[0] + (float)ha[1] * (float)hb[1];
#endif
}

// stage one timestep's h (64 KB) into LDS, coalesced 16B loads
__device__ __forceinline__ void stage64k(u32* sh, const half_t* src, int tid) {
    const uint4* s = (const uint4*)src;
    uint4* d = (uint4*)sh;
#pragma unroll
    for (int i = 0; i < 16; ++i) d[tid + i * 256] = s[tid + i * 256];
}

// ---- prep: f16 weight copies + fused biases ----
__global__ __launch_bounds__(256) void prep_kernel(
    const float* __restrict__ Whh0, const float* __restrict__ Wih1,
    const float* __restrict__ Whh1, const float* __restrict__ fcW,
    const float* __restrict__ bih0, const float* __restrict__ bhh0,
    const float* __restrict__ bih1, const float* __restrict__ bhh1,
    half_t* __restrict__ whh0h, half_t* __restrict__ wih1h,
    half_t* __restrict__ whh1h, half_t* __restrict__ fcwh,
    float* __restrict__ b0, float* __restrict__ b1)
{
    int i = blockIdx.x * 256 + threadIdx.x;
    if (i < G4 * HID) {
        whh0h[i] = (half_t)Whh0[i];
        wih1h[i] = (half_t)Wih1[i];
        whh1h[i] = (half_t)Whh1[i];
    }
    if (i < NSK * HID) fcwh[i] = (half_t)fcW[i];
    if (i < G4) { b0[i] = bih0[i] + bhh0[i]; b1[i] = bih1[i] + bhh1[i]; }
}

// ---- one pipelined tick: blocks 0..255 = layer0 step tau, 256..511 = layer1 step tau-1 ----
__global__ __launch_bounds__(256) void tick_kernel(
    int tau,
    const int* __restrict__ skills, const int* __restrict__ corrects,
    const float* __restrict__ Wih0,          // fp32 [2048][2048] (gather source)
    const half_t* __restrict__ Whh0,         // f16 [2048][512]
    const half_t* __restrict__ Wih1, const half_t* __restrict__ Whh1,
    const float* __restrict__ b0, const float* __restrict__ b1,
    float* __restrict__ c0, float* __restrict__ c1,   // [64][512] fp32
    half_t* __restrict__ h1, half_t* __restrict__ h2) // [512][HHALF]
{
    __shared__ u32 sh[HWORDS];   // 64 KB, reused: x-tile -> h-tile -> gate exchange

    const int bidx = blockIdx.x;
    const bool is_l1 = bidx >= 256;
    const int g = bidx & 255;                 // unit group: units g*2, g*2+1
    const int t = is_l1 ? tau - 1 : tau;
    if (is_l1 && tau == 0) return;
    if (!is_l1 && tau >= SEQ) return;

    const half_t* h_in; const half_t* Whh; const float* bias;
    float* cst; half_t* h_out;
    if (!is_l1) {
        h_in = (t > 0) ? h1 + (size_t)(t - 1) * HHALF : nullptr;
        Whh = Whh0; bias = b0; cst = c0; h_out = h1 + (size_t)t * HHALF;
    } else {
        h_in = (t > 0) ? h2 + (size_t)(t - 1) * HHALF : nullptr;
        Whh = Whh1; bias = b1; cst = c1; h_out = h2 + (size_t)t * HHALF;
    }

    const int tid = threadIdx.x;
    const int lane = tid & 63;               // batch index
    const int w = tid >> 6;                  // gate index: 0=i 1=f 2=g 3=o
    const int r0 = __builtin_amdgcn_readfirstlane(w * HID + g * 2);
    const int r1 = r0 + 1;

    float acc0 = bias[r0], acc1 = bias[r1];

    if (!is_l1) {
        // layer0 input term = gather of one W_ih0 column
        int sk = skills[lane * SEQ + t];
        int co = corrects[lane * SEQ + t];
        if (sk >= 0) {
            int idx = sk + NSK * ((co == 1) ? 0 : 1);
            acc0 += Wih0[(size_t)r0 * INDIM + idx];
            acc1 += Wih0[(size_t)r1 * INDIM + idx];
        }
    } else {
        // layer1 input term: dot(Wih1[r], h1[t])
        const half_t* x_in = h1 + (size_t)t * HHALF;
        stage64k(sh, x_in, tid);
        __syncthreads();
        const u32* __restrict__ ua = (const u32*)(Wih1 + (size_t)r0 * HID);
        const u32* __restrict__ ub = (const u32*)(Wih1 + (size_t)r1 * HID);
#pragma unroll 8
        for (int k2 = 0; k2 < 256; ++k2) {
            u32 xp = sh[k2 * 64 + lane];
            acc0 = dot2_(xp, ua[k2], acc0);
            acc1 = dot2_(xp, ub[k2], acc1);
        }
        __syncthreads();
    }

    if (t > 0) {
        stage64k(sh, h_in, tid);
        __syncthreads();
        const u32* __restrict__ wa = (const u32*)(Whh + (size_t)r0 * HID);
        const u32* __restrict__ wb = (const u32*)(Whh + (size_t)r1 * HID);
#pragma unroll 8
        for (int k2 = 0; k2 < 256; ++k2) {
            u32 hp = sh[k2 * 64 + lane];
            acc0 = dot2_(hp, wa[k2], acc0);
            acc1 = dot2_(hp, wb[k2], acc1);
        }
    }
    __syncthreads();

    // gate exchange: gl[gate*128 + unit*64 + lane]
    float* gl = (float*)sh;
    gl[w * 128 + lane] = acc0;
    gl[w * 128 + 64 + lane] = acc1;
    __syncthreads();

    if (w < 2) {   // wave 0 -> unit g*2, wave 1 -> unit g*2+1
        int u = g * 2 + w;
        float gi = gl[0 * 128 + w * 64 + lane];
        float gf = gl[1 * 128 + w * 64 + lane];
        float gg = gl[2 * 128 + w * 64 + lane];
        float go = gl[3 * 128 + w * 64 + lane];
        float cold = (t > 0) ? cst[lane * HID + u] : 0.0f;
        float cnew = sigmoidf_(gf) * cold + sigmoidf_(gi) * tanhf_(gg);
        float hnew = sigmoidf_(go) * tanhf_(cnew);
        cst[lane * HID + u] = cnew;
        h_out[(u >> 1) * 128 + lane * 2 + (u & 1)] = (half_t)hnew;
    }
}

// ---- projection: out[b][t][n] = sigmoid(h2[t][:,b] . fcW[n] + fcb[n]) ----
__global__ __launch_bounds__(256) void proj_kernel(
    const half_t* __restrict__ h2, const half_t* __restrict__ fcwh,
    const float* __restrict__ fcb, float* __restrict__ out)
{
    __shared__ u32 sh[HWORDS];   // 64 KB h-tile, reused as 64x65 fp32 out-stage

    const int t = blockIdx.x >> 4;
    const int nt = blockIdx.x & 15;
    const int tid = threadIdx.x;
    const int lane = tid & 63;   // batch
    const int w = tid >> 6;

    stage64k(sh, h2 + (size_t)t * HHALF, tid);
    __syncthreads();

    const int n0 = __builtin_amdgcn_readfirstlane(nt * 64 + w * 16);
    float acc[16];
#pragma unroll
    for (int j = 0; j < 16; ++j) acc[j] = 0.0f;
    const u32* wr[16];
#pragma unroll
    for (int j = 0; j < 16; ++j) wr[j] = (const u32*)(fcwh + (size_t)(n0 + j) * HID);

#pragma unroll 4
    for (int k2 = 0; k2 < 256; ++k2) {
        u32 hp = sh[k2 * 64 + lane];
#pragma unroll
        for (int j = 0; j < 16; ++j) acc[j] = dot2_(hp, wr[j][k2], acc[j]);
    }
    __syncthreads();   // all reads of sh done

    float* so = (float*)sh;      // [64][65] padded
#pragma unroll
    for (int j = 0; j < 16; ++j) so[lane * 65 + w * 16 + j] = acc[j] + fcb[n0 + j];
    __syncthreads();

    for (int i = tid; i < 4096; i += 256) {
        int b = i >> 6, n = i & 63;
        out[((size_t)b * SEQ + t) * NSK + nt * 64 + n] = sigmoidf_(so[b * 65 + n]);
    }
}

extern "C" void kernel_launch(void* const* d_in, const int* in_sizes, int n_in,
                              void* d_out, int out_size, void* d_ws, size_t ws_size,
                              hipStream_t stream) {
    (void)in_sizes; (void)n_in; (void)out_size; (void)ws_size;

    const int*   skills   = (const int*)d_in[0];
    const int*   corrects = (const int*)d_in[1];
    const float* Wih0 = (const float*)d_in[2];
    const float* Whh0 = (const float*)d_in[3];
    const float* bih0 = (const float*)d_in[4];
    const float* bhh0 = (const float*)d_in[5];
    const float* Wih1 = (const float*)d_in[6];
    const float* Whh1 = (const float*)d_in[7];
    const float* bih1 = (const float*)d_in[8];
    const float* bhh1 = (const float*)d_in[9];
    const float* fcW  = (const float*)d_in[10];
    const float* fcb  = (const float*)d_in[11];

    char* ws = (char*)d_ws;
    half_t* h1    = (half_t*)(ws + H1_OFF);
    half_t* h2    = (half_t*)(ws + H2_OFF);
    float*  c0    = (float*)(ws + C0_OFF);
    float*  c1    = (float*)(ws + C1_OFF);
    float*  b0    = (float*)(ws + B0_OFF);
    float*  b1    = (float*)(ws + B1_OFF);
    half_t* whh0h = (half_t*)(ws + WHH0_OFF);
    half_t* wih1h = (half_t*)(ws + WIH1_OFF);
    half_t* whh1h = (half_t*)(ws + WHH1_OFF);
    half_t* fcwh  = (half_t*)(ws + FCW_OFF);

    prep_kernel<<<4096, 256, 0, stream>>>(Whh0, Wih1, Whh1, fcW, bih0, bhh0,
                                          bih1, bhh1, whh0h, wih1h, whh1h, fcwh,
                                          b0, b1);

    for (int tau = 0; tau <= SEQ; ++tau) {
        tick_kernel<<<512, 256, 0, stream>>>(tau, skills, corrects, Wih0,
                                             whh0h, wih1h, whh1h, b0, b1,
                                             c0, c1, h1, h2);
    }

    proj_kernel<<<8192, 256, 0, stream>>>(h2, fcwh, fcb, (float*)d_out);
}